// Round 1
// baseline (221.347 us; speedup 1.0000x reference)
//
#include <hip/hip_runtime.h>

typedef float f32x4 __attribute__((ext_vector_type(4)));
typedef short bf16x8 __attribute__((ext_vector_type(8)));
typedef unsigned short u16x8 __attribute__((ext_vector_type(8)));

__device__ __forceinline__ unsigned short f2bf(float x) {
  union { float f; unsigned u; } c; c.f = x;
  unsigned r = c.u + 0x7fffu + ((c.u >> 16) & 1u);
  return (unsigned short)(r >> 16);
}

// ---------------------------------------------------------------------------
// Kernel 1: QKV projection.  x[16384,256] (fp32) @ [Wq|Wk|Wv] -> Qb,Kb (bf16
// [tok,32]) and Vt (bf16, V transposed: Vt[(b*256+c)*4096 + n]).
// grid (256, 5), block 256.  BM=64 tokens, BN=64 cols of 320, BK=32.
// ---------------------------------------------------------------------------
__global__ __launch_bounds__(256) void qkv_proj(
    const float* __restrict__ x,
    const float* __restrict__ Wq, const float* __restrict__ bq,
    const float* __restrict__ Wk, const float* __restrict__ bk,
    const float* __restrict__ Wv, const float* __restrict__ bv,
    unsigned short* __restrict__ Qb, unsigned short* __restrict__ Kb,
    unsigned short* __restrict__ Vt)
{
  const int mb = blockIdx.x * 64;
  const int nb = blockIdx.y * 64;
  const int t = threadIdx.x;
  const int w = t >> 6, l = t & 63, g = l >> 4, li = l & 15;

  __shared__ __align__(16) unsigned short lds_a[4 * 64 * 8];  // 4KB
  __shared__ __align__(16) unsigned short lds_b[4 * 64 * 8];  // 4KB

  f32x4 acc[4];
#pragma unroll
  for (int ct = 0; ct < 4; ++ct) acc[ct] = (f32x4){0.f, 0.f, 0.f, 0.f};

  for (int k0 = 0; k0 < 256; k0 += 32) {
    // stage A: entry (w,l) = x[mb+16w+(l&15)][k0+8*(l>>4)+j] as bf16
    {
      const int row = mb + 16 * w + li;
      const float* src = x + (size_t)row * 256 + k0 + 8 * g;
      const float4 f0 = *reinterpret_cast<const float4*>(src);
      const float4 f1 = *reinterpret_cast<const float4*>(src + 4);
      u16x8 u;
      u[0] = f2bf(f0.x); u[1] = f2bf(f0.y); u[2] = f2bf(f0.z); u[3] = f2bf(f0.w);
      u[4] = f2bf(f1.x); u[5] = f2bf(f1.y); u[6] = f2bf(f1.z); u[7] = f2bf(f1.w);
      *reinterpret_cast<u16x8*>(&lds_a[(w * 64 + l) * 8]) = u;
    }
    // stage B: entry (w,l) = W[k0+8*(l>>4)+j][nb+16w+(l&15)] as bf16
    {
      const int col = nb + 16 * w + li;
      u16x8 u;
#pragma unroll
      for (int j = 0; j < 8; ++j) {
        const int k = k0 + 8 * g + j;
        float wv;
        if (col < 32)      wv = Wq[k * 32 + col];
        else if (col < 64) wv = Wk[k * 32 + (col - 32)];
        else               wv = Wv[k * 256 + (col - 64)];
        u[j] = f2bf(wv);
      }
      *reinterpret_cast<u16x8*>(&lds_b[(w * 64 + l) * 8]) = u;
    }
    __syncthreads();
    const bf16x8 af = *reinterpret_cast<const bf16x8*>(&lds_a[(w * 64 + l) * 8]);
#pragma unroll
    for (int ct = 0; ct < 4; ++ct) {
      const bf16x8 bf = *reinterpret_cast<const bf16x8*>(&lds_b[(ct * 64 + l) * 8]);
      acc[ct] = __builtin_amdgcn_mfma_f32_16x16x32_bf16(af, bf, acc[ct], 0, 0, 0);
    }
    __syncthreads();
  }

#pragma unroll
  for (int ct = 0; ct < 4; ++ct) {
#pragma unroll
    for (int r = 0; r < 4; ++r) {
      const int row = mb + 16 * w + 4 * g + r;
      const int col = nb + 16 * ct + li;
      float v = acc[ct][r];
      if (col < 32) {
        v += bq[col];
        Qb[(size_t)row * 32 + col] = f2bf(v);
      } else if (col < 64) {
        v += bk[col - 32];
        Kb[(size_t)row * 32 + (col - 32)] = f2bf(v);
      } else {
        const int c = col - 64;
        v += bv[c];
        Vt[((size_t)((row >> 12) * 256 + c)) * 4096 + (row & 4095)] = f2bf(v);
      }
    }
  }
}

// ---------------------------------------------------------------------------
// Kernel 2: flash attention.  grid (64, 4), block 256 (4 waves).
// Block = 64 Q rows of one batch.  Per KV tile (BK=64):
//   stage K (4KB) + V (32KB) in LDS (fragment-linear layout, conflict-free),
//   wave w: QK^T + online softmax for rows 16w..16w+15, P -> LDS (bf16),
//   then PV with waves splitting DV 1x4 (wave w owns cols 64w..64w+63).
// ---------------------------------------------------------------------------
__global__ __launch_bounds__(256) void attn_fwd(
    const unsigned short* __restrict__ Qb, const unsigned short* __restrict__ Kb,
    const unsigned short* __restrict__ Vt, unsigned short* __restrict__ AO)
{
  constexpr int N = 4096;
  const int qb = blockIdx.x * 64;
  const int b  = blockIdx.y;
  const int t = threadIdx.x;
  const int w = t >> 6, l = t & 63, g = l >> 4, li = l & 15;

  __shared__ __align__(16) unsigned short lds_k[4 * 64 * 8];   // 4KB
  __shared__ __align__(16) unsigned short lds_v[32 * 64 * 8];  // 32KB
  __shared__ __align__(16) unsigned short lds_p[8 * 64 * 8];   // 8KB
  __shared__ float lds_alpha[64];
  __shared__ float lds_lsum[64];

  const bf16x8 qf = *reinterpret_cast<const bf16x8*>(
      Qb + ((size_t)(b * N + qb + 16 * w + li)) * 32 + 8 * g);

  f32x4 o[4][4];  // [row-tile][col-tile], wave w cols = 64w..64w+63
#pragma unroll
  for (int rt = 0; rt < 4; ++rt)
#pragma unroll
    for (int ct = 0; ct < 4; ++ct) o[rt][ct] = (f32x4){0.f, 0.f, 0.f, 0.f};

  float mreg[4], lreg[4];
#pragma unroll
  for (int r = 0; r < 4; ++r) { mreg[r] = -1e30f; lreg[r] = 0.f; }

  const float SC = 0.17677669529663688f * 1.44269504088896340f;  // 1/sqrt(32)*log2(e)

  for (int jt = 0; jt < N; jt += 64) {
    // ---- stage K tile: entry (w,l) = K[jt+16w+(l&15)][8*(l>>4)+j]
    {
      const int row = jt + 16 * w + li;
      reinterpret_cast<int4*>(lds_k)[w * 64 + l] =
          *reinterpret_cast<const int4*>(Kb + ((size_t)(b * N + row)) * 32 + 8 * g);
    }
    // ---- stage V tile: entry (ctg,ks,l) = Vt[ctg*16+(l&15)][jt+ks*32+8*(l>>4)+j]
#pragma unroll
    for (int ii = 0; ii < 8; ++ii) {
      const int linear = ii * 256 + t;
      const int ctg = linear >> 7, ks = (linear >> 6) & 1, ll = linear & 63;
      const int c = ctg * 16 + (ll & 15);
      const int n = jt + ks * 32 + 8 * (ll >> 4);
      reinterpret_cast<int4*>(lds_v)[(ctg * 2 + ks) * 64 + ll] =
          *reinterpret_cast<const int4*>(Vt + ((size_t)(b * 256 + c)) * N + n);
    }
    __syncthreads();

    // ---- QK^T (wave w: rows 16w..16w+15, all 64 kv cols)
    f32x4 s[4];
#pragma unroll
    for (int ct = 0; ct < 4; ++ct) {
      const bf16x8 kf = *reinterpret_cast<const bf16x8*>(&lds_k[(ct * 64 + l) * 8]);
      const f32x4 z = (f32x4){0.f, 0.f, 0.f, 0.f};
      s[ct] = __builtin_amdgcn_mfma_f32_16x16x32_bf16(qf, kf, z, 0, 0, 0);
    }

    // ---- online softmax (row = 16w + 4g + r, col = 16ct + li)
    float sv[4][4];
#pragma unroll
    for (int ct = 0; ct < 4; ++ct)
#pragma unroll
      for (int r = 0; r < 4; ++r) sv[ct][r] = s[ct][r] * SC;

    float alpha[4], rsum[4];
    unsigned short pb[4][4];
#pragma unroll
    for (int r = 0; r < 4; ++r) {
      float mx = fmaxf(fmaxf(sv[0][r], sv[1][r]), fmaxf(sv[2][r], sv[3][r]));
      mx = fmaxf(mx, __shfl_xor(mx, 1));
      mx = fmaxf(mx, __shfl_xor(mx, 2));
      mx = fmaxf(mx, __shfl_xor(mx, 4));
      mx = fmaxf(mx, __shfl_xor(mx, 8));
      const float mn = fmaxf(mreg[r], mx);
      alpha[r] = __builtin_amdgcn_exp2f(mreg[r] - mn);
      mreg[r] = mn;
      rsum[r] = 0.f;
    }
#pragma unroll
    for (int ct = 0; ct < 4; ++ct)
#pragma unroll
      for (int r = 0; r < 4; ++r) {
        const float p = __builtin_amdgcn_exp2f(sv[ct][r] - mreg[r]);
        rsum[r] += p;
        pb[ct][r] = f2bf(p);
      }
#pragma unroll
    for (int r = 0; r < 4; ++r) {
      float v = rsum[r];
      v += __shfl_xor(v, 1);
      v += __shfl_xor(v, 2);
      v += __shfl_xor(v, 4);
      v += __shfl_xor(v, 8);
      lreg[r] = lreg[r] * alpha[r] + v;
    }
    {
      const float asel = (li == 0) ? alpha[0] : ((li == 1) ? alpha[1]
                       : ((li == 2) ? alpha[2] : alpha[3]));
      if (li < 4) lds_alpha[16 * w + 4 * g + li] = asel;
    }
    // ---- write P (bf16) into MFMA-A fragment layout
#pragma unroll
    for (int ct = 0; ct < 4; ++ct)
#pragma unroll
      for (int r = 0; r < 4; ++r) {
        const int idx = ((((ct >> 1) * 4 + w) * 64 +
                          (2 * (ct & 1) + (li >> 3)) * 16 + 4 * g + r)) * 8 + (li & 7);
        lds_p[idx] = pb[ct][r];
      }
    __syncthreads();

    // ---- rescale O by alpha (rows rt*16 + 4g + r)
#pragma unroll
    for (int rt = 0; rt < 4; ++rt) {
      const float a0 = lds_alpha[rt * 16 + 4 * g + 0];
      const float a1 = lds_alpha[rt * 16 + 4 * g + 1];
      const float a2 = lds_alpha[rt * 16 + 4 * g + 2];
      const float a3 = lds_alpha[rt * 16 + 4 * g + 3];
#pragma unroll
      for (int ct = 0; ct < 4; ++ct) {
        o[rt][ct][0] *= a0; o[rt][ct][1] *= a1;
        o[rt][ct][2] *= a2; o[rt][ct][3] *= a3;
      }
    }
    // ---- PV: wave w owns DV cols 64w..64w+63 (ctg = 4w+ct); V frags disjoint
#pragma unroll
    for (int ks = 0; ks < 2; ++ks) {
      bf16x8 vf[4];
#pragma unroll
      for (int ct = 0; ct < 4; ++ct)
        vf[ct] = *reinterpret_cast<const bf16x8*>(
            &lds_v[(((4 * w + ct) * 2 + ks) * 64 + l) * 8]);
#pragma unroll
      for (int rt = 0; rt < 4; ++rt) {
        const bf16x8 pf = *reinterpret_cast<const bf16x8*>(
            &lds_p[((ks * 4 + rt) * 64 + l) * 8]);
#pragma unroll
        for (int ct = 0; ct < 4; ++ct)
          o[rt][ct] = __builtin_amdgcn_mfma_f32_16x16x32_bf16(pf, vf[ct], o[rt][ct], 0, 0, 0);
      }
    }
    __syncthreads();
  }

  {
    const float lsel = (li == 0) ? lreg[0] : ((li == 1) ? lreg[1]
                     : ((li == 2) ? lreg[2] : lreg[3]));
    if (li < 4) lds_lsum[16 * w + 4 * g + li] = lsel;
  }
  __syncthreads();

#pragma unroll
  for (int rt = 0; rt < 4; ++rt) {
    const float i0 = 1.f / lds_lsum[rt * 16 + 4 * g + 0];
    const float i1 = 1.f / lds_lsum[rt * 16 + 4 * g + 1];
    const float i2 = 1.f / lds_lsum[rt * 16 + 4 * g + 2];
    const float i3 = 1.f / lds_lsum[rt * 16 + 4 * g + 3];
#pragma unroll
    for (int ct = 0; ct < 4; ++ct) {
      const int col = 64 * w + 16 * ct + li;
      const size_t base = ((size_t)(b * N + qb + rt * 16 + 4 * g)) * 256 + col;
      AO[base + 0 * 256] = f2bf(o[rt][ct][0] * i0);
      AO[base + 1 * 256] = f2bf(o[rt][ct][1] * i1);
      AO[base + 2 * 256] = f2bf(o[rt][ct][2] * i2);
      AO[base + 3 * 256] = f2bf(o[rt][ct][3] * i3);
    }
  }
}

// ---------------------------------------------------------------------------
// Kernel 3: output projection + residual.  y = x + gamma*(AO @ Wp + bp).
// grid (256, 4), block 256.
// ---------------------------------------------------------------------------
__global__ __launch_bounds__(256) void out_proj(
    const unsigned short* __restrict__ AO,
    const float* __restrict__ Wp, const float* __restrict__ bp,
    const float* __restrict__ x, const float* __restrict__ gptr,
    float* __restrict__ y)
{
  const int mb = blockIdx.x * 64;
  const int nb = blockIdx.y * 64;
  const int t = threadIdx.x;
  const int w = t >> 6, l = t & 63, g = l >> 4, li = l & 15;

  __shared__ __align__(16) unsigned short lds_a[4 * 64 * 8];
  __shared__ __align__(16) unsigned short lds_b[4 * 64 * 8];

  f32x4 acc[4];
#pragma unroll
  for (int ct = 0; ct < 4; ++ct) acc[ct] = (f32x4){0.f, 0.f, 0.f, 0.f};

  for (int k0 = 0; k0 < 256; k0 += 32) {
    {
      const int row = mb + 16 * w + li;
      reinterpret_cast<int4*>(lds_a)[w * 64 + l] =
          *reinterpret_cast<const int4*>(AO + (size_t)row * 256 + k0 + 8 * g);
    }
    {
      const int col = nb + 16 * w + li;
      u16x8 u;
#pragma unroll
      for (int j = 0; j < 8; ++j) u[j] = f2bf(Wp[(k0 + 8 * g + j) * 256 + col]);
      *reinterpret_cast<u16x8*>(&lds_b[(w * 64 + l) * 8]) = u;
    }
    __syncthreads();
    const bf16x8 af = *reinterpret_cast<const bf16x8*>(&lds_a[(w * 64 + l) * 8]);
#pragma unroll
    for (int ct = 0; ct < 4; ++ct) {
      const bf16x8 bf = *reinterpret_cast<const bf16x8*>(&lds_b[(ct * 64 + l) * 8]);
      acc[ct] = __builtin_amdgcn_mfma_f32_16x16x32_bf16(af, bf, acc[ct], 0, 0, 0);
    }
    __syncthreads();
  }

  const float gamma = gptr[0];
#pragma unroll
  for (int ct = 0; ct < 4; ++ct) {
#pragma unroll
    for (int r = 0; r < 4; ++r) {
      const int row = mb + 16 * w + 4 * g + r;
      const int col = nb + 16 * ct + li;
      const size_t idx = (size_t)row * 256 + col;
      y[idx] = x[idx] + gamma * (acc[ct][r] + bp[col]);
    }
  }
}

extern "C" void kernel_launch(void* const* d_in, const int* in_sizes, int n_in,
                              void* d_out, int out_size, void* d_ws, size_t ws_size,
                              hipStream_t stream) {
  const float* x  = (const float*)d_in[0];
  const float* Wq = (const float*)d_in[1];
  const float* bq = (const float*)d_in[2];
  const float* Wk = (const float*)d_in[3];
  const float* bk = (const float*)d_in[4];
  const float* Wv = (const float*)d_in[5];
  const float* bv = (const float*)d_in[6];
  const float* Wp = (const float*)d_in[7];
  const float* bp = (const float*)d_in[8];
  const float* gm = (const float*)d_in[9];
  float* y = (float*)d_out;

  unsigned short* Qb = (unsigned short*)d_ws;
  unsigned short* Kb = Qb + (size_t)4 * 4096 * 32;   // 1MB each
  unsigned short* Vt = Kb + (size_t)4 * 4096 * 32;
  unsigned short* AO = Vt + (size_t)4 * 256 * 4096;  // Vt 8MB, AO 8MB

  qkv_proj<<<dim3(256, 5), 256, 0, stream>>>(x, Wq, bq, Wk, bk, Wv, bv, Qb, Kb, Vt);
  attn_fwd<<<dim3(64, 4), 256, 0, stream>>>(Qb, Kb, Vt, AO);
  out_proj<<<dim3(256, 4), 256, 0, stream>>>(AO, Wp, bp, x, gm, y);
}

// Round 2
// 158.593 us; speedup vs baseline: 1.3957x; 1.3957x over previous
//
#include <hip/hip_runtime.h>

typedef float f32x4 __attribute__((ext_vector_type(4)));
typedef short bf16x8 __attribute__((ext_vector_type(8)));
typedef unsigned short u16x8 __attribute__((ext_vector_type(8)));

__device__ __forceinline__ unsigned short f2bf(float x) {
  union { float f; unsigned u; } c; c.f = x;
  unsigned r = c.u + 0x7fffu + ((c.u >> 16) & 1u);
  return (unsigned short)(r >> 16);
}
__device__ __forceinline__ float bf2f(unsigned short v) {
  union { unsigned u; float f; } c; c.u = ((unsigned)v) << 16; return c.f;
}
__device__ __forceinline__ void gload_lds16(const void* g, void* l) {
  __builtin_amdgcn_global_load_lds((const __attribute__((address_space(1))) char*)g,
                                   (__attribute__((address_space(3))) char*)l, 16, 0, 0);
}

// ---------------------------------------------------------------------------
// Kernel 1: QKV projection.  x[16384,256] (fp32) @ [Wq|Wk|Wv] -> Qb,Kb (bf16
// [tok,32]) and Vt (bf16, V transposed: Vt[(b*256+c)*4096 + n]).
// grid (256, 5), block 256.
// ---------------------------------------------------------------------------
__global__ __launch_bounds__(256) void qkv_proj(
    const float* __restrict__ x,
    const float* __restrict__ Wq, const float* __restrict__ bq,
    const float* __restrict__ Wk, const float* __restrict__ bk,
    const float* __restrict__ Wv, const float* __restrict__ bv,
    unsigned short* __restrict__ Qb, unsigned short* __restrict__ Kb,
    unsigned short* __restrict__ Vt)
{
  const int mb = blockIdx.x * 64;
  const int nb = blockIdx.y * 64;
  const int t = threadIdx.x;
  const int w = t >> 6, l = t & 63, g = l >> 4, li = l & 15;

  __shared__ __align__(16) unsigned short lds_a[4 * 64 * 8];
  __shared__ __align__(16) unsigned short lds_b[4 * 64 * 8];

  f32x4 acc[4];
#pragma unroll
  for (int ct = 0; ct < 4; ++ct) acc[ct] = (f32x4){0.f, 0.f, 0.f, 0.f};

  for (int k0 = 0; k0 < 256; k0 += 32) {
    {
      const int row = mb + 16 * w + li;
      const float* src = x + (size_t)row * 256 + k0 + 8 * g;
      const float4 f0 = *reinterpret_cast<const float4*>(src);
      const float4 f1 = *reinterpret_cast<const float4*>(src + 4);
      u16x8 u;
      u[0] = f2bf(f0.x); u[1] = f2bf(f0.y); u[2] = f2bf(f0.z); u[3] = f2bf(f0.w);
      u[4] = f2bf(f1.x); u[5] = f2bf(f1.y); u[6] = f2bf(f1.z); u[7] = f2bf(f1.w);
      *reinterpret_cast<u16x8*>(&lds_a[(w * 64 + l) * 8]) = u;
    }
    {
      const int col = nb + 16 * w + li;
      u16x8 u;
#pragma unroll
      for (int j = 0; j < 8; ++j) {
        const int k = k0 + 8 * g + j;
        float wv;
        if (col < 32)      wv = Wq[k * 32 + col];
        else if (col < 64) wv = Wk[k * 32 + (col - 32)];
        else               wv = Wv[k * 256 + (col - 64)];
        u[j] = f2bf(wv);
      }
      *reinterpret_cast<u16x8*>(&lds_b[(w * 64 + l) * 8]) = u;
    }
    __syncthreads();
    const bf16x8 af = *reinterpret_cast<const bf16x8*>(&lds_a[(w * 64 + l) * 8]);
#pragma unroll
    for (int ct = 0; ct < 4; ++ct) {
      const bf16x8 bf = *reinterpret_cast<const bf16x8*>(&lds_b[(ct * 64 + l) * 8]);
      acc[ct] = __builtin_amdgcn_mfma_f32_16x16x32_bf16(af, bf, acc[ct], 0, 0, 0);
    }
    __syncthreads();
  }

#pragma unroll
  for (int ct = 0; ct < 4; ++ct) {
#pragma unroll
    for (int r = 0; r < 4; ++r) {
      const int row = mb + 16 * w + 4 * g + r;
      const int col = nb + 16 * ct + li;
      float v = acc[ct][r];
      if (col < 32) {
        v += bq[col];
        Qb[(size_t)row * 32 + col] = f2bf(v);
      } else if (col < 64) {
        v += bk[col - 32];
        Kb[(size_t)row * 32 + (col - 32)] = f2bf(v);
      } else {
        const int c = col - 64;
        v += bv[c];
        Vt[((size_t)((row >> 12) * 256 + c)) * 4096 + (row & 4095)] = f2bf(v);
      }
    }
  }
}

// ---------------------------------------------------------------------------
// Kernel 2: flash attention with KV-split.  grid (4, 64, S), block 256.
// Each block: 64 Q rows x KV range [sp*4096/S, +4096/S).  Writes
// unnormalized O (bf16) + per-row m,l for the combine in out_proj.
// K/V staged via global_load_lds (lane-linear LDS layout).
// ---------------------------------------------------------------------------
template <int S>
__global__ __launch_bounds__(256) void attn_fwd(
    const unsigned short* __restrict__ Qb, const unsigned short* __restrict__ Kb,
    const unsigned short* __restrict__ Vt,
    unsigned short* __restrict__ Opart, float* __restrict__ Mpart,
    float* __restrict__ Lpart)
{
  constexpr int N = 4096;
  constexpr int SPAN = N / S;
  const int b  = blockIdx.x;
  const int qb = blockIdx.y * 64;
  const int sp = blockIdx.z;
  const int t = threadIdx.x;
  const int w = t >> 6, l = t & 63, g = l >> 4, li = l & 15;

  __shared__ __align__(16) int4 lds_k4[256];    // 4KB  K tile
  __shared__ __align__(16) int4 lds_v4[2048];   // 32KB V tile
  __shared__ __align__(16) unsigned short lds_p[4096];  // 8KB P
  __shared__ float lds_alpha[64];

  const bf16x8 qf = *reinterpret_cast<const bf16x8*>(
      Qb + ((size_t)(b * N + qb + 16 * w + li)) * 32 + 8 * g);

  const int jt0 = sp * SPAN;
  const unsigned short* srcK = Kb + ((size_t)(b * N + jt0 + 16 * w + li)) * 32 + 8 * g;
  const unsigned short* srcV[8];
#pragma unroll
  for (int ii = 0; ii < 8; ++ii) {
    const int p = ii * 4 + w;
    srcV[ii] = Vt + ((size_t)(b * 256 + (p >> 1) * 16 + li)) * N + jt0 + (p & 1) * 32 + 8 * g;
  }

  f32x4 o[4][4];
#pragma unroll
  for (int rt = 0; rt < 4; ++rt)
#pragma unroll
    for (int ct = 0; ct < 4; ++ct) o[rt][ct] = (f32x4){0.f, 0.f, 0.f, 0.f};

  float mreg[4], lreg[4];
#pragma unroll
  for (int r = 0; r < 4; ++r) { mreg[r] = -1e30f; lreg[r] = 0.f; }

  const float SC = 0.17677669529663688f * 1.44269504088896340f;

  for (int tt = 0; tt < SPAN / 64; ++tt) {
    const int jt = tt * 64;
    // ---- async stage K+V into LDS
    gload_lds16(srcK + (size_t)jt * 32, &lds_k4[w * 64]);
#pragma unroll
    for (int ii = 0; ii < 8; ++ii)
      gload_lds16(srcV[ii] + jt, &lds_v4[(ii * 4 + w) * 64]);
    __syncthreads();

    // ---- QK^T (wave w: rows 16w..16w+15, all 64 kv cols)
    f32x4 s[4];
#pragma unroll
    for (int ct = 0; ct < 4; ++ct) {
      const bf16x8 kf = *reinterpret_cast<const bf16x8*>(&lds_k4[ct * 64 + l]);
      const f32x4 z = (f32x4){0.f, 0.f, 0.f, 0.f};
      s[ct] = __builtin_amdgcn_mfma_f32_16x16x32_bf16(qf, kf, z, 0, 0, 0);
    }

    float sv[4][4];
#pragma unroll
    for (int ct = 0; ct < 4; ++ct)
#pragma unroll
      for (int r = 0; r < 4; ++r) sv[ct][r] = s[ct][r] * SC;

    float alpha[4], rsum[4];
    unsigned short pb[4][4];
#pragma unroll
    for (int r = 0; r < 4; ++r) {
      float mx = fmaxf(fmaxf(sv[0][r], sv[1][r]), fmaxf(sv[2][r], sv[3][r]));
      mx = fmaxf(mx, __shfl_xor(mx, 1));
      mx = fmaxf(mx, __shfl_xor(mx, 2));
      mx = fmaxf(mx, __shfl_xor(mx, 4));
      mx = fmaxf(mx, __shfl_xor(mx, 8));
      const float mn = fmaxf(mreg[r], mx);
      alpha[r] = __builtin_amdgcn_exp2f(mreg[r] - mn);
      mreg[r] = mn;
      rsum[r] = 0.f;
    }
#pragma unroll
    for (int ct = 0; ct < 4; ++ct)
#pragma unroll
      for (int r = 0; r < 4; ++r) {
        const float p = __builtin_amdgcn_exp2f(sv[ct][r] - mreg[r]);
        rsum[r] += p;
        pb[ct][r] = f2bf(p);
      }
#pragma unroll
    for (int r = 0; r < 4; ++r) {
      float v = rsum[r];
      v += __shfl_xor(v, 1);
      v += __shfl_xor(v, 2);
      v += __shfl_xor(v, 4);
      v += __shfl_xor(v, 8);
      lreg[r] = lreg[r] * alpha[r] + v;
    }
    {
      const float asel = (li == 0) ? alpha[0] : ((li == 1) ? alpha[1]
                       : ((li == 2) ? alpha[2] : alpha[3]));
      if (li < 4) lds_alpha[16 * w + 4 * g + li] = asel;
    }
#pragma unroll
    for (int ct = 0; ct < 4; ++ct)
#pragma unroll
      for (int r = 0; r < 4; ++r) {
        const int idx = ((((ct >> 1) * 4 + w) * 64 +
                          (2 * (ct & 1) + (li >> 3)) * 16 + 4 * g + r)) * 8 + (li & 7);
        lds_p[idx] = pb[ct][r];
      }
    __syncthreads();

#pragma unroll
    for (int rt = 0; rt < 4; ++rt) {
      const float a0 = lds_alpha[rt * 16 + 4 * g + 0];
      const float a1 = lds_alpha[rt * 16 + 4 * g + 1];
      const float a2 = lds_alpha[rt * 16 + 4 * g + 2];
      const float a3 = lds_alpha[rt * 16 + 4 * g + 3];
#pragma unroll
      for (int ct = 0; ct < 4; ++ct) {
        o[rt][ct][0] *= a0; o[rt][ct][1] *= a1;
        o[rt][ct][2] *= a2; o[rt][ct][3] *= a3;
      }
    }
#pragma unroll
    for (int ks = 0; ks < 2; ++ks) {
      bf16x8 vf[4];
#pragma unroll
      for (int ct = 0; ct < 4; ++ct)
        vf[ct] = *reinterpret_cast<const bf16x8*>(&lds_v4[((4 * w + ct) * 2 + ks) * 64 + l]);
#pragma unroll
      for (int rt = 0; rt < 4; ++rt) {
        const bf16x8 pf = *reinterpret_cast<const bf16x8*>(
            &lds_p[((ks * 4 + rt) * 64 + l) * 8]);
#pragma unroll
        for (int ct = 0; ct < 4; ++ct)
          o[rt][ct] = __builtin_amdgcn_mfma_f32_16x16x32_bf16(pf, vf[ct], o[rt][ct], 0, 0, 0);
      }
    }
    __syncthreads();
  }

  // ---- per-row m,l
  {
    const size_t mlbase = ((size_t)(sp * 4 + b)) * N + qb + 16 * w + 4 * g;
    if (li < 4) {
      const float msel = (li == 0) ? mreg[0] : ((li == 1) ? mreg[1]
                       : ((li == 2) ? mreg[2] : mreg[3]));
      const float lsel = (li == 0) ? lreg[0] : ((li == 1) ? lreg[1]
                       : ((li == 2) ? lreg[2] : lreg[3]));
      Mpart[mlbase + li] = msel;
      Lpart[mlbase + li] = lsel;
    }
  }

  // ---- O epilogue: transpose through LDS (reuse V buffer), coalesced store
  unsigned short* po = reinterpret_cast<unsigned short*>(lds_v4);
#pragma unroll
  for (int rt = 0; rt < 4; ++rt)
#pragma unroll
    for (int ct = 0; ct < 4; ++ct)
#pragma unroll
      for (int r = 0; r < 4; ++r)
        po[(rt * 16 + 4 * g + r) * 256 + 64 * w + 16 * ct + li] = f2bf(o[rt][ct][r]);
  __syncthreads();
  const size_t obase = ((size_t)((sp * 4 + b)) * N + qb) * 256;
  int4* dst = reinterpret_cast<int4*>(Opart + obase);
  const int4* src = reinterpret_cast<const int4*>(po);
#pragma unroll
  for (int ii = 0; ii < 8; ++ii) dst[ii * 256 + t] = src[ii * 256 + t];
}

// ---------------------------------------------------------------------------
// Kernel 3: split-combine + output projection + residual.
// y = x + gamma * ((sum_s w_s O_s) @ Wp + bp),  w_s = exp2(m_s - M) / L.
// grid (256, 4), block 256.
// ---------------------------------------------------------------------------
template <int S>
__global__ __launch_bounds__(256) void out_proj(
    const unsigned short* __restrict__ Opart, const float* __restrict__ Mpart,
    const float* __restrict__ Lpart,
    const float* __restrict__ Wp, const float* __restrict__ bp,
    const float* __restrict__ x, const float* __restrict__ gptr,
    float* __restrict__ y)
{
  const int mb = blockIdx.x * 64;
  const int nb = blockIdx.y * 64;
  const int t = threadIdx.x;
  const int w = t >> 6, l = t & 63, g = l >> 4, li = l & 15;

  __shared__ __align__(16) unsigned short lds_a[4 * 64 * 8];
  __shared__ __align__(16) unsigned short lds_b[4 * 64 * 8];
  __shared__ float lds_wt[4][64];

  if (t < 64) {
    const int tok = mb + t;
    const int b = tok >> 12, n = tok & 4095;
    float m[S], lv[S];
#pragma unroll
    for (int s = 0; s < S; ++s) {
      m[s]  = Mpart[((size_t)(s * 4 + b)) * 4096 + n];
      lv[s] = Lpart[((size_t)(s * 4 + b)) * 4096 + n];
    }
    float M = m[0];
#pragma unroll
    for (int s = 1; s < S; ++s) M = fmaxf(M, m[s]);
    float wv[S], L = 0.f;
#pragma unroll
    for (int s = 0; s < S; ++s) { wv[s] = __builtin_amdgcn_exp2f(m[s] - M); L += wv[s] * lv[s]; }
    const float inv = 1.f / L;
#pragma unroll
    for (int s = 0; s < S; ++s) lds_wt[s][t] = wv[s] * inv;
  }
  __syncthreads();

  f32x4 acc[4];
#pragma unroll
  for (int ct = 0; ct < 4; ++ct) acc[ct] = (f32x4){0.f, 0.f, 0.f, 0.f};

  for (int k0 = 0; k0 < 256; k0 += 32) {
    {
      const int lrow = 16 * w + li;
      const int tok = mb + lrow;
      const int b = tok >> 12, n = tok & 4095;
      float a8[8];
#pragma unroll
      for (int j = 0; j < 8; ++j) a8[j] = 0.f;
#pragma unroll
      for (int s = 0; s < S; ++s) {
        const u16x8 raw = *reinterpret_cast<const u16x8*>(
            Opart + (((size_t)(s * 4 + b)) * 4096 + n) * 256 + k0 + 8 * g);
        const float wt = lds_wt[s][lrow];
#pragma unroll
        for (int j = 0; j < 8; ++j) a8[j] += wt * bf2f(raw[j]);
      }
      u16x8 u;
#pragma unroll
      for (int j = 0; j < 8; ++j) u[j] = f2bf(a8[j]);
      *reinterpret_cast<u16x8*>(&lds_a[(w * 64 + l) * 8]) = u;
    }
    {
      const int col = nb + 16 * w + li;
      u16x8 u;
#pragma unroll
      for (int j = 0; j < 8; ++j) u[j] = f2bf(Wp[(k0 + 8 * g + j) * 256 + col]);
      *reinterpret_cast<u16x8*>(&lds_b[(w * 64 + l) * 8]) = u;
    }
    __syncthreads();
    const bf16x8 af = *reinterpret_cast<const bf16x8*>(&lds_a[(w * 64 + l) * 8]);
#pragma unroll
    for (int ct = 0; ct < 4; ++ct) {
      const bf16x8 bf = *reinterpret_cast<const bf16x8*>(&lds_b[(ct * 64 + l) * 8]);
      acc[ct] = __builtin_amdgcn_mfma_f32_16x16x32_bf16(af, bf, acc[ct], 0, 0, 0);
    }
    __syncthreads();
  }

  const float gamma = gptr[0];
#pragma unroll
  for (int ct = 0; ct < 4; ++ct) {
#pragma unroll
    for (int r = 0; r < 4; ++r) {
      const int row = mb + 16 * w + 4 * g + r;
      const int col = nb + 16 * ct + li;
      const size_t idx = (size_t)row * 256 + col;
      y[idx] = x[idx] + gamma * (acc[ct][r] + bp[col]);
    }
  }
}

extern "C" void kernel_launch(void* const* d_in, const int* in_sizes, int n_in,
                              void* d_out, int out_size, void* d_ws, size_t ws_size,
                              hipStream_t stream) {
  const float* x  = (const float*)d_in[0];
  const float* Wq = (const float*)d_in[1];
  const float* bq = (const float*)d_in[2];
  const float* Wk = (const float*)d_in[3];
  const float* bk = (const float*)d_in[4];
  const float* Wv = (const float*)d_in[5];
  const float* bv = (const float*)d_in[6];
  const float* Wp = (const float*)d_in[7];
  const float* bp = (const float*)d_in[8];
  const float* gm = (const float*)d_in[9];
  float* y = (float*)d_out;

  unsigned short* Qb = (unsigned short*)d_ws;
  unsigned short* Kb = Qb + (size_t)4 * 4096 * 32;
  unsigned short* Vt = Kb + (size_t)4 * 4096 * 32;
  unsigned short* Op = Vt + (size_t)4 * 256 * 4096;
  const size_t base_bytes = ((size_t)4 * 4096 * 32 * 2 + (size_t)4 * 256 * 4096) * 2;

  qkv_proj<<<dim3(256, 5), 256, 0, stream>>>(x, Wq, bq, Wk, bk, Wv, bv, Qb, Kb, Vt);

  const size_t per_split = (size_t)4 * 4096 * 256 * 2 + (size_t)4 * 4096 * 4 * 2;
  int S = 1;
  if (ws_size >= base_bytes + 4 * per_split) S = 4;
  else if (ws_size >= base_bytes + 2 * per_split) S = 2;

  if (S == 4) {
    float* Mp = (float*)(Op + (size_t)4 * 4 * 4096 * 256);
    float* Lp = Mp + (size_t)4 * 4 * 4096;
    attn_fwd<4><<<dim3(4, 64, 4), 256, 0, stream>>>(Qb, Kb, Vt, Op, Mp, Lp);
    out_proj<4><<<dim3(256, 4), 256, 0, stream>>>(Op, Mp, Lp, Wp, bp, x, gm, y);
  } else if (S == 2) {
    float* Mp = (float*)(Op + (size_t)2 * 4 * 4096 * 256);
    float* Lp = Mp + (size_t)2 * 4 * 4096;
    attn_fwd<2><<<dim3(4, 64, 2), 256, 0, stream>>>(Qb, Kb, Vt, Op, Mp, Lp);
    out_proj<2><<<dim3(256, 4), 256, 0, stream>>>(Op, Mp, Lp, Wp, bp, x, gm, y);
  } else {
    float* Mp = (float*)(Op + (size_t)1 * 4 * 4096 * 256);
    float* Lp = Mp + (size_t)1 * 4 * 4096;
    attn_fwd<1><<<dim3(4, 64, 1), 256, 0, stream>>>(Qb, Kb, Vt, Op, Mp, Lp);
    out_proj<1><<<dim3(256, 4), 256, 0, stream>>>(Op, Mp, Lp, Wp, bp, x, gm, y);
  }
}

// Round 3
// 146.205 us; speedup vs baseline: 1.5140x; 1.0847x over previous
//
#include <hip/hip_runtime.h>

typedef float f32x4 __attribute__((ext_vector_type(4)));
typedef short bf16x8 __attribute__((ext_vector_type(8)));
typedef unsigned short u16x8 __attribute__((ext_vector_type(8)));

__device__ __forceinline__ unsigned short f2bf(float x) {
  union { float f; unsigned u; } c; c.f = x;
  unsigned r = c.u + 0x7fffu + ((c.u >> 16) & 1u);
  return (unsigned short)(r >> 16);
}
__device__ __forceinline__ float bf2f(unsigned short v) {
  union { unsigned u; float f; } c; c.u = ((unsigned)v) << 16; return c.f;
}
__device__ __forceinline__ void gload_lds16(const void* g, void* l) {
  __builtin_amdgcn_global_load_lds((const __attribute__((address_space(1))) char*)g,
                                   (__attribute__((address_space(3))) char*)l, 16, 0, 0);
}

// ---------------------------------------------------------------------------
// Kernel 1: QKV projection (unchanged).
// ---------------------------------------------------------------------------
__global__ __launch_bounds__(256) void qkv_proj(
    const float* __restrict__ x,
    const float* __restrict__ Wq, const float* __restrict__ bq,
    const float* __restrict__ Wk, const float* __restrict__ bk,
    const float* __restrict__ Wv, const float* __restrict__ bv,
    unsigned short* __restrict__ Qb, unsigned short* __restrict__ Kb,
    unsigned short* __restrict__ Vt)
{
  const int mb = blockIdx.x * 64;
  const int nb = blockIdx.y * 64;
  const int t = threadIdx.x;
  const int w = t >> 6, l = t & 63, g = l >> 4, li = l & 15;

  __shared__ __align__(16) unsigned short lds_a[4 * 64 * 8];
  __shared__ __align__(16) unsigned short lds_b[4 * 64 * 8];

  f32x4 acc[4];
#pragma unroll
  for (int ct = 0; ct < 4; ++ct) acc[ct] = (f32x4){0.f, 0.f, 0.f, 0.f};

  for (int k0 = 0; k0 < 256; k0 += 32) {
    {
      const int row = mb + 16 * w + li;
      const float* src = x + (size_t)row * 256 + k0 + 8 * g;
      const float4 f0 = *reinterpret_cast<const float4*>(src);
      const float4 f1 = *reinterpret_cast<const float4*>(src + 4);
      u16x8 u;
      u[0] = f2bf(f0.x); u[1] = f2bf(f0.y); u[2] = f2bf(f0.z); u[3] = f2bf(f0.w);
      u[4] = f2bf(f1.x); u[5] = f2bf(f1.y); u[6] = f2bf(f1.z); u[7] = f2bf(f1.w);
      *reinterpret_cast<u16x8*>(&lds_a[(w * 64 + l) * 8]) = u;
    }
    {
      const int col = nb + 16 * w + li;
      u16x8 u;
#pragma unroll
      for (int j = 0; j < 8; ++j) {
        const int k = k0 + 8 * g + j;
        float wv;
        if (col < 32)      wv = Wq[k * 32 + col];
        else if (col < 64) wv = Wk[k * 32 + (col - 32)];
        else               wv = Wv[k * 256 + (col - 64)];
        u[j] = f2bf(wv);
      }
      *reinterpret_cast<u16x8*>(&lds_b[(w * 64 + l) * 8]) = u;
    }
    __syncthreads();
    const bf16x8 af = *reinterpret_cast<const bf16x8*>(&lds_a[(w * 64 + l) * 8]);
#pragma unroll
    for (int ct = 0; ct < 4; ++ct) {
      const bf16x8 bf = *reinterpret_cast<const bf16x8*>(&lds_b[(ct * 64 + l) * 8]);
      acc[ct] = __builtin_amdgcn_mfma_f32_16x16x32_bf16(af, bf, acc[ct], 0, 0, 0);
    }
    __syncthreads();
  }

#pragma unroll
  for (int ct = 0; ct < 4; ++ct) {
#pragma unroll
    for (int r = 0; r < 4; ++r) {
      const int row = mb + 16 * w + 4 * g + r;
      const int col = nb + 16 * ct + li;
      float v = acc[ct][r];
      if (col < 32) {
        v += bq[col];
        Qb[(size_t)row * 32 + col] = f2bf(v);
      } else if (col < 64) {
        v += bk[col - 32];
        Kb[(size_t)row * 32 + (col - 32)] = f2bf(v);
      } else {
        const int c = col - 64;
        v += bv[c];
        Vt[((size_t)((row >> 12) * 256 + c)) * 4096 + (row & 4095)] = f2bf(v);
      }
    }
  }
}

// ---------------------------------------------------------------------------
// Kernel 2: flash attention, 8-wave blocks (128 Q rows), KV-split S.
// grid (32, 4, S), block 512.  Wave w: softmax rows 16w..16w+15;
// PV split (wr=w>>2, wc=w&3): rows 64wr..+63, cols 64wc..+63.
// Defer-max: skip O-rescale when no row's max grew by > THR (log2 units).
// ---------------------------------------------------------------------------
template <int S>
__global__ __launch_bounds__(512, 4) void attn_fwd(
    const unsigned short* __restrict__ Qb, const unsigned short* __restrict__ Kb,
    const unsigned short* __restrict__ Vt,
    unsigned short* __restrict__ Opart, float* __restrict__ Mpart,
    float* __restrict__ Lpart)
{
  constexpr int N = 4096;
  constexpr int SPAN = N / S;
  constexpr float THR = 8.0f;
  const int qb = blockIdx.x * 128;
  const int b  = blockIdx.y;
  const int sp = blockIdx.z;
  const int t = threadIdx.x;
  const int w = t >> 6, l = t & 63, g = (l >> 4), li = l & 15;
  const int wr = w >> 2, wc = w & 3;

  __shared__ __align__(16) int4 lds_k4[256];             // 4KB  K tile (64x32)
  __shared__ __align__(16) int4 lds_v4[2048];            // 32KB V tile (64x256)
  __shared__ __align__(16) unsigned short lds_p[8192];   // 16KB P (128x64)
  __shared__ float lds_alpha[128];
  __shared__ float lds_lsum[128];
  __shared__ int lds_need[8];

  const bf16x8 qf = *reinterpret_cast<const bf16x8*>(
      Qb + ((size_t)(b * N + qb + 16 * w + li)) * 32 + 8 * g);

  const int jt0 = sp * SPAN;
  const unsigned short* baseK = Kb + ((size_t)(b * N + jt0 + 16 * w + li)) * 32 + 8 * g;
  const unsigned short* baseV = Vt + ((size_t)(b * 256 + li)) * N + jt0 + 8 * g;
  int offV[4];
#pragma unroll
  for (int ii = 0; ii < 4; ++ii) {
    const int p = w * 4 + ii;  // p = ctg*2+ks
    offV[ii] = ((p >> 1) * 16) * N + (p & 1) * 32;
  }

  f32x4 o[4][4];
#pragma unroll
  for (int rt = 0; rt < 4; ++rt)
#pragma unroll
    for (int ct = 0; ct < 4; ++ct) o[rt][ct] = (f32x4){0.f, 0.f, 0.f, 0.f};

  float mreg[4], lreg[4];
#pragma unroll
  for (int r = 0; r < 4; ++r) { mreg[r] = -1e30f; lreg[r] = 0.f; }

  const float SC = 0.17677669529663688f * 1.44269504088896340f;  // 1/sqrt(32)*log2e

  for (int tt = 0; tt < SPAN / 64; ++tt) {
    const int jt = tt * 64;
    // ---- async stage K (waves 0-3) + V (all waves) into LDS
    if (t < 256) gload_lds16(baseK + (size_t)jt * 32, &lds_k4[w * 64]);
#pragma unroll
    for (int ii = 0; ii < 4; ++ii)
      gload_lds16(baseV + offV[ii] + jt, &lds_v4[(w * 4 + ii) * 64]);
    __syncthreads();

    // ---- QK^T: wave w rows 16w..16w+15, cols = all 64 kv
    f32x4 s[4];
    const f32x4 z = (f32x4){0.f, 0.f, 0.f, 0.f};
#pragma unroll
    for (int ct = 0; ct < 4; ++ct) {
      const bf16x8 kf = *reinterpret_cast<const bf16x8*>(&lds_k4[ct * 64 + l]);
      s[ct] = __builtin_amdgcn_mfma_f32_16x16x32_bf16(qf, kf, z, 0, 0, 0);
    }

    float sv[4][4];
#pragma unroll
    for (int ct = 0; ct < 4; ++ct)
#pragma unroll
      for (int r = 0; r < 4; ++r) sv[ct][r] = s[ct][r] * SC;

    // ---- row maxima + defer-max decision
    float mx[4];
    bool need = false;
#pragma unroll
    for (int r = 0; r < 4; ++r) {
      float m = fmaxf(fmaxf(sv[0][r], sv[1][r]), fmaxf(sv[2][r], sv[3][r]));
      m = fmaxf(m, __shfl_xor(m, 1));
      m = fmaxf(m, __shfl_xor(m, 2));
      m = fmaxf(m, __shfl_xor(m, 4));
      m = fmaxf(m, __shfl_xor(m, 8));
      mx[r] = m;
      need = need || (m > mreg[r] + THR);
    }
    float alpha[4];
    const bool wneed = (__ballot(need) != 0ull);
    if (wneed) {
#pragma unroll
      for (int r = 0; r < 4; ++r) {
        const float mn = fmaxf(mreg[r], mx[r]);
        alpha[r] = __builtin_amdgcn_exp2f(mreg[r] - mn);
        mreg[r] = mn;
      }
    } else {
#pragma unroll
      for (int r = 0; r < 4; ++r) alpha[r] = 1.0f;
    }

    float rsum[4];
    unsigned short pb[4][4];
#pragma unroll
    for (int r = 0; r < 4; ++r) rsum[r] = 0.f;
#pragma unroll
    for (int ct = 0; ct < 4; ++ct)
#pragma unroll
      for (int r = 0; r < 4; ++r) {
        const float p = __builtin_amdgcn_exp2f(sv[ct][r] - mreg[r]);
        rsum[r] += p;
        pb[ct][r] = f2bf(p);
      }
#pragma unroll
    for (int r = 0; r < 4; ++r) {
      float v = rsum[r];
      v += __shfl_xor(v, 1);
      v += __shfl_xor(v, 2);
      v += __shfl_xor(v, 4);
      v += __shfl_xor(v, 8);
      lreg[r] = lreg[r] * alpha[r] + v;
    }
    if (l == 0) lds_need[w] = wneed ? 1 : 0;
    {
      const float asel = (li == 0) ? alpha[0] : ((li == 1) ? alpha[1]
                       : ((li == 2) ? alpha[2] : alpha[3]));
      if (li < 4) lds_alpha[16 * w + 4 * g + li] = asel;
    }
    // ---- P -> LDS in MFMA-A fragment layout ([rt=w][ks=ct>>1])
#pragma unroll
    for (int ct = 0; ct < 4; ++ct)
#pragma unroll
      for (int r = 0; r < 4; ++r) {
        const int idx = ((w * 2 + (ct >> 1)) * 64 +
                         (2 * (ct & 1) + (li >> 3)) * 16 + 4 * g + r) * 8 + (li & 7);
        lds_p[idx] = pb[ct][r];
      }
    __syncthreads();

    // ---- conditional O rescale (rows 64wr+16rt+4g+r)
    const int needAny = lds_need[4 * wr] | lds_need[4 * wr + 1] |
                        lds_need[4 * wr + 2] | lds_need[4 * wr + 3];
    if (needAny) {
#pragma unroll
      for (int rt = 0; rt < 4; ++rt) {
        const float a0 = lds_alpha[64 * wr + 16 * rt + 4 * g + 0];
        const float a1 = lds_alpha[64 * wr + 16 * rt + 4 * g + 1];
        const float a2 = lds_alpha[64 * wr + 16 * rt + 4 * g + 2];
        const float a3 = lds_alpha[64 * wr + 16 * rt + 4 * g + 3];
#pragma unroll
        for (int ct = 0; ct < 4; ++ct) {
          o[rt][ct][0] *= a0; o[rt][ct][1] *= a1;
          o[rt][ct][2] *= a2; o[rt][ct][3] *= a3;
        }
      }
    }
    // ---- PV: rows 64wr..+63 x cols 64wc..+63
#pragma unroll
    for (int ks = 0; ks < 2; ++ks) {
      bf16x8 vf[4], pf[4];
#pragma unroll
      for (int ct = 0; ct < 4; ++ct)
        vf[ct] = *reinterpret_cast<const bf16x8*>(&lds_v4[((4 * wc + ct) * 2 + ks) * 64 + l]);
#pragma unroll
      for (int rt = 0; rt < 4; ++rt)
        pf[rt] = *reinterpret_cast<const bf16x8*>(
            &lds_p[(((4 * wr + rt) * 2 + ks) * 64 + l) * 8]);
#pragma unroll
      for (int rt = 0; rt < 4; ++rt)
#pragma unroll
        for (int ct = 0; ct < 4; ++ct)
          o[rt][ct] = __builtin_amdgcn_mfma_f32_16x16x32_bf16(pf[rt], vf[ct], o[rt][ct], 0, 0, 0);
    }
    __syncthreads();
  }

  // ---- per-row m,l partials + lsum to LDS
  {
    const size_t mlbase = ((size_t)(sp * 4 + b)) * N + qb + 16 * w + 4 * g;
    const float msel = (li == 0) ? mreg[0] : ((li == 1) ? mreg[1]
                     : ((li == 2) ? mreg[2] : mreg[3]));
    const float lsel = (li == 0) ? lreg[0] : ((li == 1) ? lreg[1]
                     : ((li == 2) ? lreg[2] : lreg[3]));
    if (li < 4) {
      Mpart[mlbase + li] = msel;
      Lpart[mlbase + li] = lsel;
      lds_lsum[16 * w + 4 * g + li] = lsel;
    }
  }
  __syncthreads();

  // ---- O epilogue: normalize, transpose through LDS (reuse V buffer), store
  unsigned short* po = reinterpret_cast<unsigned short*>(lds_v4);
#pragma unroll
  for (int pass = 0; pass < 2; ++pass) {
    if (wr == pass) {
#pragma unroll
      for (int rt = 0; rt < 4; ++rt) {
        const float i0 = 1.f / lds_lsum[64 * wr + 16 * rt + 4 * g + 0];
        const float i1 = 1.f / lds_lsum[64 * wr + 16 * rt + 4 * g + 1];
        const float i2 = 1.f / lds_lsum[64 * wr + 16 * rt + 4 * g + 2];
        const float i3 = 1.f / lds_lsum[64 * wr + 16 * rt + 4 * g + 3];
#pragma unroll
        for (int ct = 0; ct < 4; ++ct) {
          const int col = 64 * wc + 16 * ct + li;
          po[(16 * rt + 4 * g + 0) * 256 + col] = f2bf(o[rt][ct][0] * i0);
          po[(16 * rt + 4 * g + 1) * 256 + col] = f2bf(o[rt][ct][1] * i1);
          po[(16 * rt + 4 * g + 2) * 256 + col] = f2bf(o[rt][ct][2] * i2);
          po[(16 * rt + 4 * g + 3) * 256 + col] = f2bf(o[rt][ct][3] * i3);
        }
      }
    }
    __syncthreads();
    int4* dst = reinterpret_cast<int4*>(
        Opart + ((size_t)((sp * 4 + b)) * N + qb + pass * 64) * 256);
    const int4* src = reinterpret_cast<const int4*>(po);
#pragma unroll
    for (int ii = 0; ii < 4; ++ii) dst[ii * 512 + t] = src[ii * 512 + t];
    __syncthreads();
  }
}

// ---------------------------------------------------------------------------
// Kernel 3: split-combine + output projection + residual (unchanged).
// ---------------------------------------------------------------------------
template <int S>
__global__ __launch_bounds__(256) void out_proj(
    const unsigned short* __restrict__ Opart, const float* __restrict__ Mpart,
    const float* __restrict__ Lpart,
    const float* __restrict__ Wp, const float* __restrict__ bp,
    const float* __restrict__ x, const float* __restrict__ gptr,
    float* __restrict__ y)
{
  const int mb = blockIdx.x * 64;
  const int nb = blockIdx.y * 64;
  const int t = threadIdx.x;
  const int w = t >> 6, l = t & 63, g = l >> 4, li = l & 15;

  __shared__ __align__(16) unsigned short lds_a[4 * 64 * 8];
  __shared__ __align__(16) unsigned short lds_b[4 * 64 * 8];
  __shared__ float lds_wt[4][64];

  if (t < 64) {
    const int tok = mb + t;
    const int b = tok >> 12, n = tok & 4095;
    float m[S], lv[S];
#pragma unroll
    for (int s = 0; s < S; ++s) {
      m[s]  = Mpart[((size_t)(s * 4 + b)) * 4096 + n];
      lv[s] = Lpart[((size_t)(s * 4 + b)) * 4096 + n];
    }
    float M = m[0];
#pragma unroll
    for (int s = 1; s < S; ++s) M = fmaxf(M, m[s]);
    float wv[S], L = 0.f;
#pragma unroll
    for (int s = 0; s < S; ++s) { wv[s] = __builtin_amdgcn_exp2f(m[s] - M); L += wv[s] * lv[s]; }
    const float inv = 1.f / L;
#pragma unroll
    for (int s = 0; s < S; ++s) lds_wt[s][t] = wv[s] * lv[s] * inv;
  }
  __syncthreads();

  f32x4 acc[4];
#pragma unroll
  for (int ct = 0; ct < 4; ++ct) acc[ct] = (f32x4){0.f, 0.f, 0.f, 0.f};

  for (int k0 = 0; k0 < 256; k0 += 32) {
    {
      const int lrow = 16 * w + li;
      const int tok = mb + lrow;
      const int b = tok >> 12, n = tok & 4095;
      float a8[8];
#pragma unroll
      for (int j = 0; j < 8; ++j) a8[j] = 0.f;
#pragma unroll
      for (int s = 0; s < S; ++s) {
        const u16x8 raw = *reinterpret_cast<const u16x8*>(
            Opart + (((size_t)(s * 4 + b)) * 4096 + n) * 256 + k0 + 8 * g);
        const float wt = lds_wt[s][lrow];
#pragma unroll
        for (int j = 0; j < 8; ++j) a8[j] += wt * bf2f(raw[j]);
      }
      u16x8 u;
#pragma unroll
      for (int j = 0; j < 8; ++j) u[j] = f2bf(a8[j]);
      *reinterpret_cast<u16x8*>(&lds_a[(w * 64 + l) * 8]) = u;
    }
    {
      const int col = nb + 16 * w + li;
      u16x8 u;
#pragma unroll
      for (int j = 0; j < 8; ++j) u[j] = f2bf(Wp[(k0 + 8 * g + j) * 256 + col]);
      *reinterpret_cast<u16x8*>(&lds_b[(w * 64 + l) * 8]) = u;
    }
    __syncthreads();
    const bf16x8 af = *reinterpret_cast<const bf16x8*>(&lds_a[(w * 64 + l) * 8]);
#pragma unroll
    for (int ct = 0; ct < 4; ++ct) {
      const bf16x8 bf = *reinterpret_cast<const bf16x8*>(&lds_b[(ct * 64 + l) * 8]);
      acc[ct] = __builtin_amdgcn_mfma_f32_16x16x32_bf16(af, bf, acc[ct], 0, 0, 0);
    }
    __syncthreads();
  }

  const float gamma = gptr[0];
#pragma unroll
  for (int ct = 0; ct < 4; ++ct) {
#pragma unroll
    for (int r = 0; r < 4; ++r) {
      const int row = mb + 16 * w + 4 * g + r;
      const int col = nb + 16 * ct + li;
      const size_t idx = (size_t)row * 256 + col;
      y[idx] = x[idx] + gamma * (acc[ct][r] + bp[col]);
    }
  }
}

extern "C" void kernel_launch(void* const* d_in, const int* in_sizes, int n_in,
                              void* d_out, int out_size, void* d_ws, size_t ws_size,
                              hipStream_t stream) {
  const float* x  = (const float*)d_in[0];
  const float* Wq = (const float*)d_in[1];
  const float* bq = (const float*)d_in[2];
  const float* Wk = (const float*)d_in[3];
  const float* bk = (const float*)d_in[4];
  const float* Wv = (const float*)d_in[5];
  const float* bv = (const float*)d_in[6];
  const float* Wp = (const float*)d_in[7];
  const float* bp = (const float*)d_in[8];
  const float* gm = (const float*)d_in[9];
  float* y = (float*)d_out;

  unsigned short* Qb = (unsigned short*)d_ws;
  unsigned short* Kb = Qb + (size_t)4 * 4096 * 32;
  unsigned short* Vt = Kb + (size_t)4 * 4096 * 32;
  unsigned short* Op = Vt + (size_t)4 * 256 * 4096;
  const size_t base_bytes = ((size_t)4 * 4096 * 32 * 2 + (size_t)4 * 256 * 4096) * 2;

  qkv_proj<<<dim3(256, 5), 256, 0, stream>>>(x, Wq, bq, Wk, bk, Wv, bv, Qb, Kb, Vt);

  const size_t per_split = (size_t)4 * 4096 * 256 * 2 + (size_t)4 * 4096 * 4 * 2;
  int S = 1;
  if (ws_size >= base_bytes + 4 * per_split) S = 4;
  else if (ws_size >= base_bytes + 2 * per_split) S = 2;

  if (S == 4) {
    float* Mp = (float*)(Op + (size_t)4 * 4 * 4096 * 256);
    float* Lp = Mp + (size_t)4 * 4 * 4096;
    attn_fwd<4><<<dim3(32, 4, 4), 512, 0, stream>>>(Qb, Kb, Vt, Op, Mp, Lp);
    out_proj<4><<<dim3(256, 4), 256, 0, stream>>>(Op, Mp, Lp, Wp, bp, x, gm, y);
  } else if (S == 2) {
    float* Mp = (float*)(Op + (size_t)2 * 4 * 4096 * 256);
    float* Lp = Mp + (size_t)2 * 4 * 4096;
    attn_fwd<2><<<dim3(32, 4, 2), 512, 0, stream>>>(Qb, Kb, Vt, Op, Mp, Lp);
    out_proj<2><<<dim3(256, 4), 256, 0, stream>>>(Op, Mp, Lp, Wp, bp, x, gm, y);
  } else {
    float* Mp = (float*)(Op + (size_t)1 * 4 * 4096 * 256);
    float* Lp = Mp + (size_t)1 * 4 * 4096;
    attn_fwd<1><<<dim3(32, 4, 1), 512, 0, stream>>>(Qb, Kb, Vt, Op, Mp, Lp);
    out_proj<1><<<dim3(256, 4), 256, 0, stream>>>(Op, Mp, Lp, Wp, bp, x, gm, y);
  }
}